// Round 8
// baseline (2964.327 us; speedup 1.0000x reference)
//
#include <hip/hip_runtime.h>
#include <hip/hip_fp16.h>

#define N_NODES 100000
#define N_EDGES 1600000
#define NFEAT   256
#define NHID    128
#define LATENT  64

#define NBUCKET 782              // ceil(N_NODES / 128), 128 rows per bucket
#define NBLKH   196              // histogram/scatter blocks
#define CHUNK   8192             // edges per histogram/scatter block
#define NHIST   (NBUCKET * NBLKH)   // 153272
#define NHISTT  300              // hist-scan tiles of 512 (300*512 >= NHIST)

typedef __attribute__((ext_vector_type(8))) short s16x8;
typedef __attribute__((ext_vector_type(4))) float f32x4;

__device__ __forceinline__ unsigned short f2bf(float f) {
    union { float f; unsigned u; } v; v.f = f;
    unsigned r = v.u + 0x7fffu + ((v.u >> 16) & 1u);   // RNE (finite inputs)
    return (unsigned short)(r >> 16);
}
// packed-bf16 lane extraction: lo = u<<16, hi = u & 0xffff0000 (1 VALU each)
__device__ __forceinline__ float bflo(unsigned u) {
    union { unsigned x; float f; } v; v.x = u << 16; return v.f;
}
__device__ __forceinline__ float bfhi(unsigned u) {
    union { unsigned x; float f; } v; v.x = u & 0xffff0000u; return v.f;
}
// edge weight in [0,1): fp16 sans sign bit = 15 bits
__device__ __forceinline__ float w15_decode(unsigned pv) {
    return __half2float(__ushort_as_half((unsigned short)(pv & 0x7fffu)));
}

// inclusive 512-wide block scan (ping-pong); block-uniform call sites only
__device__ __forceinline__ int incl_scan512(int v, int t, int (&s)[2][512]) {
    s[0][t] = v;
    __syncthreads();
    int p = 0;
    for (int off = 1; off < 512; off <<= 1) {
        int x = s[p][t];
        if (t >= off) x += s[p][t - off];
        s[p ^ 1][t] = x;
        p ^= 1;
        __syncthreads();
    }
    return s[p][t];
}

// ------------------------------------------------------- weight pre-convert
// fp32 [K][N] (optionally split at ncol0 between B0/B1) -> bf16 in MFMA
// fragment-block order: out[((nt*K8 + kc)*16 + m)*8 + j] = B[kc*8+j][nt*16+m]

__device__ __forceinline__ void prep_body(
    int c, int K, int Ntot, int ncol0, int ldb0, int ldb1,
    const float* __restrict__ B0, const float* __restrict__ B1,
    unsigned short* __restrict__ out)
{
    int K8 = K >> 3;
    int total = (Ntot >> 4) * K8 * 16;
    if (c >= total) return;
    int m  = c & 15;
    int kc = (c >> 4) % K8;
    int nt = (c >> 4) / K8;
    int col = nt * 16 + m;
    const float* src; int ld, cc;
    if (col < ncol0) { src = B0; ld = ldb0; cc = col; }
    else             { src = B1; ld = ldb1; cc = col - ncol0; }
    s16x8 v;
    #pragma unroll
    for (int j = 0; j < 8; ++j)
        v[j] = (short)f2bf(src[(size_t)(kc * 8 + j) * ld + cc]);
    *(s16x8*)&out[(size_t)c * 8] = v;
}

// ---------------------------------------------------------------- k_pre:
// blocks 0..195: LDS coarse-bucket histogram -> histG[bucket][block]
// blocks 196+ : weight pre-convert w1/w2/w3
// (history: gemm1 fusion REGRESSED (LDS co-alloc); split tmp payload
//  REGRESSED (2x scattered stores); cooperative all-in-one REGRESSED
//  (grid.sync = cross-XCD drain, 383us). This split chain is the optimum
//  found so far.)

__global__ __launch_bounds__(256) void k_pre(
    const int* __restrict__ rows, int* __restrict__ histG,
    const float* __restrict__ gc1_w, unsigned short* __restrict__ w1p,
    const float* __restrict__ gc2_w, unsigned short* __restrict__ w2p,
    const float* __restrict__ mu_w, const float* __restrict__ lv_w,
    unsigned short* __restrict__ w3p)
{
    int b = blockIdx.x;
    int t = threadIdx.x;
    if (b < NBLKH) {
        __shared__ int hist[NBUCKET];
        for (int i = t; i < NBUCKET; i += 256) hist[i] = 0;
        __syncthreads();
        int base = b * CHUNK;
        #pragma unroll 4
        for (int i = 0; i < CHUNK / 256; ++i) {
            int e = base + i * 256 + t;
            if (e < N_EDGES) {
                int r = rows[e];
                atomicAdd(&hist[r >> 7], 1);
            }
        }
        __syncthreads();
        for (int i = t; i < NBUCKET; i += 256)
            histG[(size_t)i * NBLKH + b] = hist[i];
    } else if (b < NBLKH + 16) {
        prep_body((b - NBLKH) * 256 + t, NFEAT, NHID, NHID, NHID, NHID, gc1_w, gc1_w, w1p);
    } else if (b < NBLKH + 24) {
        prep_body((b - NBLKH - 16) * 256 + t, NHID, NHID, NHID, NHID, NHID, gc2_w, gc2_w, w2p);
    } else {
        prep_body((b - NBLKH - 24) * 256 + t, NHID, NHID, LATENT, LATENT, LATENT, mu_w, lv_w, w3p);
    }
}

// ---------------------------------------------------------------- scans

__global__ __launch_bounds__(512) void k_scanA(
    const int* __restrict__ histG, int* __restrict__ hist_excl,
    int* __restrict__ hbsum)
{
    __shared__ int s[2][512];
    int b = blockIdx.x, t = threadIdx.x;
    int i = b * 512 + t;
    int v = (i < NHIST) ? histG[i] : 0;
    int incl = incl_scan512(v, t, s);
    if (i < NHIST) hist_excl[i] = incl - v;
    if (t == 511) hbsum[b] = incl;
}

__global__ __launch_bounds__(512) void k_scanC(
    const int* __restrict__ hist_excl, const int* __restrict__ hbsum,
    int* __restrict__ scanned)
{
    __shared__ int s[2][512];
    __shared__ int sbase;
    int b = blockIdx.x, t = threadIdx.x;
    int v = (t < NHISTT) ? hbsum[t] : 0;
    int incl = incl_scan512(v, t, s);
    if (t == b) sbase = incl - v;      // exclusive tile-sum prefix for tile b
    __syncthreads();
    int base = sbase;
    int i = b * 512 + t;
    if (i < NHIST) scanned[i] = hist_excl[i] + base;
}

// --------------------------------------------------- scatter pass A (no atomics
// on global): each block owns exclusive (block,bucket) segments from the scan;
// LDS cursors only. Writes are sequential per segment -> full-line writeback.
// Output tmp is BUCKET-grouped (rows mixed within a bucket slice) -- that is
// all the bucket-LDS spmm needs, so there is NO row-sort pass anymore.

__global__ __launch_bounds__(256) void k_scatterA(
    const int* __restrict__ rows, const int* __restrict__ cols,
    const float* __restrict__ ew, const int* __restrict__ scanned,
    uint2* __restrict__ tmp)
{
    __shared__ int cur[NBUCKET];
    int b = blockIdx.x, t = threadIdx.x;
    for (int i = t; i < NBUCKET; i += 256)
        cur[i] = scanned[(size_t)i * NBLKH + b];
    __syncthreads();
    int base = b * CHUNK;
    #pragma unroll 4
    for (int i = 0; i < CHUNK / 256; ++i) {
        int e = base + i * 256 + t;
        if (e < N_EDGES) {
            int r = rows[e];
            unsigned hv = (unsigned)__half_as_ushort(__float2half(ew[e]));
            unsigned pv = ((unsigned)cols[e] << 15) | (hv & 0x7fffu);
            int p = atomicAdd(&cur[r >> 7], 1);
            tmp[p] = make_uint2(pv, (unsigned)r);
        }
    }
}

// ---------------------------------------------------------------- MFMA GEMM
// C[M x 128] = A[M x K] @ B[K x 128], bf16 MFMA 16x16x32, fp32 accumulate.
// BM=32 BN=128 BK=64, 256 threads = 4 waves. B pre-converted fragment blocks.

template<int AMODE, int OMODE>
__global__ __launch_bounds__(256) void k_gemm(
    int K, const float* __restrict__ A32, const unsigned short* __restrict__ A16,
    const unsigned short* __restrict__ Bpre,
    unsigned short* __restrict__ C16,
    float* __restrict__ C0, float* __restrict__ C1,
    const float* __restrict__ bias0, const float* __restrict__ bias1)
{
    __shared__ unsigned short As[2048];  // [rt2][kc8][m16][j8]
    __shared__ unsigned short Bs[8192];  // [nt8][kc8][n16][j8]

    const int t    = threadIdx.x;
    const int m0   = blockIdx.x * 32;
    const int lane = t & 63;
    const int w    = t >> 6;
    const int rt   = w & 1;
    const int ntb  = (w >> 1) * 4;
    const int fm   = lane & 15;
    const int q    = lane >> 4;
    const int K8   = K >> 3;

    f32x4 acc[4] = {};

    for (int kt = 0; kt < K; kt += 64) {
        {
            int r = t >> 3, kc = t & 7;
            int lo = ((r >> 4) * 8 + kc) * 128 + (r & 15) * 8;
            if (AMODE == 0) {
                const float* g = A32 + (size_t)(m0 + r) * K + kt + kc * 8;
                float4 a = *(const float4*)g;
                float4 b = *(const float4*)(g + 4);
                s16x8 v;
                v[0] = (short)f2bf(a.x); v[1] = (short)f2bf(a.y);
                v[2] = (short)f2bf(a.z); v[3] = (short)f2bf(a.w);
                v[4] = (short)f2bf(b.x); v[5] = (short)f2bf(b.y);
                v[6] = (short)f2bf(b.z); v[7] = (short)f2bf(b.w);
                *(s16x8*)&As[lo] = v;
            } else {
                const unsigned short* g = A16 + (size_t)(m0 + r) * 128 + kt + kc * 8;
                *(s16x8*)&As[lo] = *(const s16x8*)g;
            }
        }
        {
            int ktc = kt >> 3;
            #pragma unroll
            for (int i = 0; i < 4; ++i) {
                int c  = t + i * 256;
                int nt = c >> 7, kc = (c >> 4) & 7, m = c & 15;
                const unsigned short* g =
                    Bpre + ((size_t)(nt * K8 + ktc + kc) * 16 + m) * 8;
                *(s16x8*)&Bs[c * 8] = *(const s16x8*)g;
            }
        }
        __syncthreads();
        #pragma unroll
        for (int kk = 0; kk < 2; ++kk) {
            int kcq = kk * 4 + q;
            s16x8 a = *(const s16x8*)&As[(rt * 8 + kcq) * 128 + fm * 8];
            #pragma unroll
            for (int i = 0; i < 4; ++i) {
                s16x8 b = *(const s16x8*)&Bs[((ntb + i) * 8 + kcq) * 128 + fm * 8];
                acc[i] = __builtin_amdgcn_mfma_f32_16x16x32_bf16(a, b, acc[i], 0, 0, 0);
            }
        }
        __syncthreads();
    }

    // epilogue: C/D layout col=lane&15, row=q*4+reg
    #pragma unroll
    for (int i = 0; i < 4; ++i) {
        int col = (ntb + i) * 16 + fm;
        #pragma unroll
        for (int j = 0; j < 4; ++j) {
            int r = m0 + rt * 16 + q * 4 + j;
            float v = acc[i][j];
            if (OMODE == 0) {
                C16[(size_t)r * 128 + col] = f2bf(v);
            } else {
                if (col < 64) C0[(size_t)r * 64 + col]      = v + bias0[col];
                else          C1[(size_t)r * 64 + col - 64] = v + bias1[col - 64];
            }
        }
    }
}

// ---------------------------------------------------------------- SpMM (bucket)
// One block per bucket (128 rows). LDS fp32 accumulator acc[128][128] (64KB).
// Consumes the bucket-grouped tmp slice directly (rows mixed -> no row sort
// needed; k_passB and ecw/row_ptr deleted). Per edge: the whole wave loads
// the 256B support row coalesced (4B/lane), then 2 LDS float atomicAdds per
// lane into the edge's row. Epilogue: bias+relu+bf16-pack, 32KB contiguous
// store per block.

__global__ __launch_bounds__(256) void k_spmmB(
    const int* __restrict__ scanned, const uint2* __restrict__ tmp,
    const unsigned short* __restrict__ sup, const float* __restrict__ bias,
    unsigned short* __restrict__ out)
{
    __shared__ float acc[128][NHID];   // 64 KB
    int b    = blockIdx.x;
    int t    = threadIdx.x;
    int wid  = t >> 6;
    int lane = t & 63;
    int r0   = b * 128;

    int beg = scanned[(size_t)b * NBLKH];
    int end = (b + 1 < NBUCKET) ? scanned[(size_t)(b + 1) * NBLKH] : N_EDGES;

    // zero accumulator (float4 stores)
    {
        float4* a4 = (float4*)&acc[0][0];
        #pragma unroll
        for (int i = 0; i < 16; ++i)
            a4[t + i * 256] = make_float4(0.f, 0.f, 0.f, 0.f);
    }
    __syncthreads();

    // main: each wave takes 4 consecutive edges, stride 16 across 4 waves
    int n16 = beg + ((end - beg) & ~15);
    for (int e = beg + wid * 4; e < n16; e += 16) {
        uint2 t0 = tmp[e + 0];
        uint2 t1 = tmp[e + 1];
        uint2 t2 = tmp[e + 2];
        uint2 t3 = tmp[e + 3];
        unsigned u0 = *(const unsigned*)(sup + (size_t)(t0.x >> 15) * NHID + lane * 2);
        unsigned u1 = *(const unsigned*)(sup + (size_t)(t1.x >> 15) * NHID + lane * 2);
        unsigned u2 = *(const unsigned*)(sup + (size_t)(t2.x >> 15) * NHID + lane * 2);
        unsigned u3 = *(const unsigned*)(sup + (size_t)(t3.x >> 15) * NHID + lane * 2);
        float w0 = w15_decode(t0.x), w1 = w15_decode(t1.x);
        float w2 = w15_decode(t2.x), w3 = w15_decode(t3.x);
        int f = lane * 2;
        atomicAdd(&acc[t0.y & 127][f],     w0 * bflo(u0));
        atomicAdd(&acc[t0.y & 127][f + 1], w0 * bfhi(u0));
        atomicAdd(&acc[t1.y & 127][f],     w1 * bflo(u1));
        atomicAdd(&acc[t1.y & 127][f + 1], w1 * bfhi(u1));
        atomicAdd(&acc[t2.y & 127][f],     w2 * bflo(u2));
        atomicAdd(&acc[t2.y & 127][f + 1], w2 * bfhi(u2));
        atomicAdd(&acc[t3.y & 127][f],     w3 * bflo(u3));
        atomicAdd(&acc[t3.y & 127][f + 1], w3 * bfhi(u3));
    }
    // tail (< 16 edges): one edge per wave, stride 4
    for (int e = n16 + wid; e < end; e += 4) {
        uint2 tv = tmp[e];
        unsigned u = *(const unsigned*)(sup + (size_t)(tv.x >> 15) * NHID + lane * 2);
        float w = w15_decode(tv.x);
        int f = lane * 2;
        atomicAdd(&acc[tv.y & 127][f],     w * bflo(u));
        atomicAdd(&acc[tv.y & 127][f + 1], w * bfhi(u));
    }
    __syncthreads();

    // epilogue: thread t -> row t>>1, feat half (t&1)*64; bias+relu+pack
    int r    = t >> 1;
    int fb   = (t & 1) * 64;
    int rr   = r0 + r;
    if (rr < N_NODES) {
        #pragma unroll
        for (int k = 0; k < 8; ++k) {
            int f = fb + k * 8;
            uint2 pv;
            unsigned o[8];
            #pragma unroll
            for (int j = 0; j < 8; ++j) {
                float v = acc[r][f + j] + bias[f + j];
                v = v > 0.f ? v : 0.f;
                o[j] = (unsigned)f2bf(v);
            }
            pv.x = o[0] | (o[1] << 16);
            pv.y = o[2] | (o[3] << 16);
            uint2 pw;
            pw.x = o[4] | (o[5] << 16);
            pw.y = o[6] | (o[7] << 16);
            *(uint2*)(out + (size_t)rr * NHID + f)     = pv;
            *(uint2*)(out + (size_t)rr * NHID + f + 4) = pw;
        }
    }
}

// ---------------------------------------------------------------- launch

extern "C" void kernel_launch(void* const* d_in, const int* in_sizes, int n_in,
                              void* d_out, int out_size, void* d_ws, size_t ws_size,
                              hipStream_t stream) {
    const float* x     = (const float*)d_in[0];
    const int*   ei    = (const int*)  d_in[1];
    const float* ew    = (const float*)d_in[2];
    const float* gc1_w = (const float*)d_in[3];
    const float* gc1_b = (const float*)d_in[4];
    const float* gc2_w = (const float*)d_in[5];
    const float* gc2_b = (const float*)d_in[6];
    const float* mu_w  = (const float*)d_in[7];
    const float* mu_b  = (const float*)d_in[8];
    const float* lv_w  = (const float*)d_in[9];
    const float* lv_b  = (const float*)d_in[10];
    float* out = (float*)d_out;

    const int* rows = ei;
    const int* cols = ei + N_EDGES;

    char* p = (char*)d_ws;
    auto alloc = [&](size_t bytes) {
        char* r = p;
        p += (bytes + 255) & ~(size_t)255;
        return r;
    };
    int*      histG     = (int*)     alloc((size_t)NHIST * 4);
    int*      hist_excl = (int*)     alloc((size_t)NHIST * 4);
    int*      hbsum     = (int*)     alloc((size_t)NHISTT * 4);
    int*      scanned   = (int*)     alloc((size_t)NHIST * 4);
    uint2*    tmp       = (uint2*)   alloc((size_t)N_EDGES * 8);
    unsigned short* w1p    = (unsigned short*)alloc((size_t)NFEAT * NHID * 2);
    unsigned short* w2p    = (unsigned short*)alloc((size_t)NHID * NHID * 2);
    unsigned short* w3p    = (unsigned short*)alloc((size_t)NHID * NHID * 2);
    unsigned short* bufSup = (unsigned short*)alloc((size_t)N_NODES * NHID * 2);
    unsigned short* bufH   = (unsigned short*)alloc((size_t)N_NODES * NHID * 2);
    (void)ws_size; (void)n_in; (void)in_sizes; (void)out_size;

    // histogram || weight prep
    k_pre<<<NBLKH + 32, 256, 0, stream>>>(rows, histG,
                                          gc1_w, w1p, gc2_w, w2p, mu_w, lv_w, w3p);
    // hist scan
    k_scanA<<<NHISTT, 512, 0, stream>>>(histG, hist_excl, hbsum);
    k_scanC<<<NHISTT, 512, 0, stream>>>(hist_excl, hbsum, scanned);
    // single reorder pass -> bucket-grouped tmp (no row sort needed)
    k_scatterA<<<NBLKH, 256, 0, stream>>>(rows, cols, ew, scanned, tmp);

    // gc1
    k_gemm<0, 0><<<N_NODES / 32, 256, 0, stream>>>(NFEAT, x, nullptr, w1p,
                                                   bufSup, nullptr, nullptr, nullptr, nullptr);
    k_spmmB<<<NBUCKET, 256, 0, stream>>>(scanned, tmp, bufSup, gc1_b, bufH);
    // gc2
    k_gemm<1, 0><<<N_NODES / 32, 256, 0, stream>>>(NHID, nullptr, bufH, w2p,
                                                   bufSup, nullptr, nullptr, nullptr, nullptr);
    k_spmmB<<<NBUCKET, 256, 0, stream>>>(scanned, tmp, bufSup, gc2_b, bufH);
    // mu / log_var fused projection
    k_gemm<1, 1><<<N_NODES / 32, 256, 0, stream>>>(NHID, nullptr, bufH, w3p,
                                                   nullptr, out, out + (size_t)N_NODES * LATENT,
                                                   mu_b, lv_b);
}